// Round 11
// baseline (158.019 us; speedup 1.0000x reference)
//
#include <hip/hip_runtime.h>

typedef __attribute__((ext_vector_type(8))) _Float16 f16x8;
typedef __attribute__((ext_vector_type(4))) _Float16 f16x4;
typedef __attribute__((ext_vector_type(2))) __fp16 fp16x2;
typedef __attribute__((ext_vector_type(4))) float f32x4;

union U4 { f16x4 v; fp16x2 p[2]; };

__device__ __forceinline__ f16x4 cvt4(f32x4 a) {
  U4 u;
  u.p[0] = __builtin_amdgcn_cvt_pkrtz(a.x, a.y);
  u.p[1] = __builtin_amdgcn_cvt_pkrtz(a.z, a.w);
  return u.v;
}
__device__ __forceinline__ float dot4(f32x4 a, f32x4 b) {
  return a.x * b.x + a.y * b.y + a.z * b.z + a.w * b.w;
}

// K=32 zero-shuffle B<->C chaining (k-permuted W in LDS, proven r10) +
// PAIR-SCHEDULED aggregation to cap arch-VGPR live set under the 128 clamp:
//   pairs (0,1)/(2,3)/(4,5) share aggregation inputs {h0,h1,h2}/{h1..h4}/{h3,h4,h5};
//   only 2 transient ag frags (16 regs) exist at a time, and outputs commit
//   in-place into hC except h1/h3 (one 8-reg temp each, one-pair lifetime).
// Peak live ~105 regs (r10's ag[6][2] materialization peaked ~145 -> 176MB spill).
__global__ __launch_bounds__(256, 2) void gcn_fused(
    const float* __restrict__ x,
    const float* __restrict__ W1, const float* __restrict__ B1,
    const float* __restrict__ W2, const float* __restrict__ B2,
    const float* __restrict__ W3, const float* __restrict__ B3,
    const float* __restrict__ W4, const float* __restrict__ B4,
    const float* __restrict__ fcw, const float* __restrict__ fcb,
    float* __restrict__ out)
{
  __shared__ __align__(16) _Float16 wlds[4][4][2][64][8];  // [l][nt][kt][lane][8], k-permuted, cb-scaled
  __shared__ float blds[4][64];

  const int tid  = threadIdx.x;
  const int lane = tid & 63;
  const int c    = lane & 15;   // A-row local / C col (batch)
  const int q    = lane >> 4;   // k-group / C row-group
  const int w    = tid >> 6;
  const int b    = blockIdx.x * 64 + w * 16 + c;  // this lane's batch row

  const float* Wg[4] = {W1, W2, W3, W4};

  // ---- stage cb_l*W_l into LDS in k-permuted fragment order (r10-verbatim) ----
#pragma unroll
  for (int l = 0; l < 4; ++l) {
    const float s = (l < 2) ? (1.f / 3.f) : 0.25f;
#pragma unroll
    for (int rep = 0; rep < 4; ++rep) {
      const int idx = rep * 1024 + tid * 4;       // flat f32 idx in 64x64 W_l
      const int row = idx >> 6, col = idx & 63;   // out-feat row, in-feat col
      const int nt = row >> 4, ca = row & 15;
      const int kt = col >> 5, ss = (col >> 4) & 1, qq = (col >> 2) & 3;
      f32x4 v = *(const f32x4*)(Wg[l] + idx);
      v *= s;
      *(f16x4*)&wlds[l][nt][kt][qq * 16 + ca][ss * 4] = cvt4(v);
    }
  }
  {  // biases: wave w stages layer w's bias (no runtime-indexed pointer array)
    const float* bp = (w == 0) ? B1 : (w == 1) ? B2 : (w == 2) ? B3 : B4;
    blds[w][lane] = bp[lane];
  }

  // ---- x -> hC (C-frag-order f16 regs) + residual fc-dot q-partials ----
  f16x4 hC[6][4];   // [node][m]: lane (c,q) holds feats m*16+4q+{0..3} of batch b
  float pacc[6];
  {
    const float* xr = x + (size_t)b * 384 + q * 4;
#pragma unroll
    for (int n = 0; n < 6; ++n) {
      float p = 0.f;
#pragma unroll
      for (int m = 0; m < 4; ++m) {
        f32x4 v  = *(const f32x4*)(xr + n * 64 + m * 16);
        f32x4 fw = *(const f32x4*)(fcw + n * 64 + m * 16 + q * 4);
        p += dot4(v, fw);
        hC[n][m] = cvt4(v);
      }
      pacc[n] = p;
    }
  }
  __syncthreads();  // staging visible; only barrier in the kernel

  // aggregate in f16 C-frag space: ag = dbl*self + nb1 + nb2 (cb folded into W)
  auto mkag = [&](f16x8* dst, int n, int m1, int m2, bool dbl) {
#pragma unroll
    for (int kt = 0; kt < 2; ++kt) {
      f16x4 lo = hC[m1][2 * kt]     + hC[m2][2 * kt];
      f16x4 hi = hC[m1][2 * kt + 1] + hC[m2][2 * kt + 1];
      if (dbl) { lo = lo + hC[n][2 * kt] + hC[n][2 * kt];
                 hi = hi + hC[n][2 * kt + 1] + hC[n][2 * kt + 1]; }
      else     { lo = lo + hC[n][2 * kt];
                 hi = hi + hC[n][2 * kt + 1]; }
      dst[kt] = __builtin_shufflevector(lo, hi, 0, 1, 2, 3, 4, 5, 6, 7);
    }
  };

#pragma unroll
  for (int l = 0; l < 4; ++l) {
    // 2 MFMAs per node per nt; wf/bias re-read from LDS per pair (regs, not cached)
    auto mmpair = [&](const f16x8* agA, const f16x8* agB, f16x4* outA, f16x4* outB) {
#pragma unroll
      for (int nt = 0; nt < 4; ++nt) {
        const f16x8 wf0  = *(const f16x8*)&wlds[l][nt][0][lane][0];
        const f16x8 wf1  = *(const f16x8*)&wlds[l][nt][1][lane][0];
        const f32x4 bias = *(const f32x4*)&blds[l][nt * 16 + q * 4];
        f32x4 a = __builtin_amdgcn_mfma_f32_16x16x32_f16(wf0, agA[0], bias, 0, 0, 0);
        a = __builtin_amdgcn_mfma_f32_16x16x32_f16(wf1, agA[1], a, 0, 0, 0);
        f32x4 d = __builtin_amdgcn_mfma_f32_16x16x32_f16(wf0, agB[0], bias, 0, 0, 0);
        d = __builtin_amdgcn_mfma_f32_16x16x32_f16(wf1, agB[1], d, 0, 0, 0);
        f32x4 ra, rd;
#pragma unroll
        for (int e = 0; e < 4; ++e) { ra[e] = fmaxf(a[e], 0.f); rd[e] = fmaxf(d[e], 0.f); }
        outA[nt] = cvt4(ra);
        outB[nt] = cvt4(rd);
      }
    };
    auto mmlast = [&](const f16x8* agA, const f16x8* agB, int na, int nb) {
#pragma unroll
      for (int nt = 0; nt < 4; ++nt) {
        const f16x8 wf0  = *(const f16x8*)&wlds[3][nt][0][lane][0];
        const f16x8 wf1  = *(const f16x8*)&wlds[3][nt][1][lane][0];
        const f32x4 bias = *(const f32x4*)&blds[3][nt * 16 + q * 4];
        f32x4 a = __builtin_amdgcn_mfma_f32_16x16x32_f16(wf0, agA[0], bias, 0, 0, 0);
        a = __builtin_amdgcn_mfma_f32_16x16x32_f16(wf1, agA[1], a, 0, 0, 0);
        f32x4 d = __builtin_amdgcn_mfma_f32_16x16x32_f16(wf0, agB[0], bias, 0, 0, 0);
        d = __builtin_amdgcn_mfma_f32_16x16x32_f16(wf1, agB[1], d, 0, 0, 0);
        const f32x4 fwa = *(const f32x4*)(fcw + na * 64 + nt * 16 + q * 4);
        const f32x4 fwb = *(const f32x4*)(fcw + nb * 64 + nt * 16 + q * 4);
#pragma unroll
        for (int e = 0; e < 4; ++e) {
          pacc[na] += fmaxf(a[e], 0.f) * fwa[e];
          pacc[nb] += fmaxf(d[e], 0.f) * fwb[e];
        }
      }
    };

    const bool dbl = (l >= 2);
    f16x8 agA[2], agB[2];
    if (l < 3) {
      f16x4 t1[4], t3[4];
      // pair (0,1): inputs {h0,h1,h2}; h0 dies here -> direct commit; h1 -> temp
      mkag(agA, 0, 1, 2, dbl); mkag(agB, 1, 0, 2, dbl);
      mmpair(agA, agB, hC[0], t1);
      // pair (2,3): inputs old {h1,h2,h3,h4}; then h1 commits; h2 direct; h3 -> temp
      mkag(agA, 2, 1, 3, dbl); mkag(agB, 3, 2, 4, dbl);
#pragma unroll
      for (int m = 0; m < 4; ++m) hC[1][m] = t1[m];
      mmpair(agA, agB, hC[2], t3);
      // pair (4,5): inputs old {h3,h4,h5}; then h3 commits; h4,h5 direct
      mkag(agA, 4, 3, 5, dbl); mkag(agB, 5, 3, 4, dbl);
#pragma unroll
      for (int m = 0; m < 4; ++m) hC[3][m] = t3[m];
      mmpair(agA, agB, hC[4], hC[5]);
    } else {
      mkag(agA, 0, 1, 2, true); mkag(agB, 1, 0, 2, true);
      mmlast(agA, agB, 0, 1);
      mkag(agA, 2, 1, 3, true); mkag(agB, 3, 2, 4, true);
      mmlast(agA, agB, 2, 3);
      mkag(agA, 4, 3, 5, true); mkag(agB, 5, 3, 4, true);
      mmlast(agA, agB, 4, 5);
    }
  }

  // ---- epilogue: reduce fc-dot over q-groups, sigmoid, store ----
#pragma unroll
  for (int n = 0; n < 6; ++n) {
    float t = pacc[n];
    t += __shfl_xor(t, 16, 64);
    t += __shfl_xor(t, 32, 64);
    if (q == 0) {
      const float vz = t + fcb[n];
      out[(size_t)b * 6 + n] = 1.f / (1.f + __expf(-vz));
    }
  }
}

extern "C" void kernel_launch(void* const* d_in, const int* in_sizes, int n_in,
                              void* d_out, int out_size, void* d_ws, size_t ws_size,
                              hipStream_t stream) {
  const float* x   = (const float*)d_in[0];
  const float* W1  = (const float*)d_in[1];
  const float* B1  = (const float*)d_in[2];
  const float* W2  = (const float*)d_in[3];
  const float* B2  = (const float*)d_in[4];
  const float* W3  = (const float*)d_in[5];
  const float* B3  = (const float*)d_in[6];
  const float* W4  = (const float*)d_in[7];
  const float* B4  = (const float*)d_in[8];
  const float* fcw = (const float*)d_in[9];
  const float* fcb = (const float*)d_in[10];
  float* out = (float*)d_out;

  const int batch  = in_sizes[0] / 384;   // 131072
  const int blocks = batch / 64;          // 4 waves x 16 batch rows per block
  hipLaunchKernelGGL(gcn_fused, dim3(blocks), dim3(256), 0, stream,
                     x, W1, B1, W2, B2, W3, B3, W4, B4, fcw, fcb, out);
}

// Round 12
// 128.311 us; speedup vs baseline: 1.2315x; 1.2315x over previous
//
#include <hip/hip_runtime.h>

typedef __attribute__((ext_vector_type(8))) _Float16 f16x8;
typedef __attribute__((ext_vector_type(4))) _Float16 f16x4;
typedef __attribute__((ext_vector_type(2))) __fp16 fp16x2;
typedef __attribute__((ext_vector_type(4))) float f32x4;

union U4 { f16x4 v; fp16x2 p[2]; };

__device__ __forceinline__ f16x4 cvt4(f32x4 a) {
  U4 u;
  u.p[0] = __builtin_amdgcn_cvt_pkrtz(a.x, a.y);
  u.p[1] = __builtin_amdgcn_cvt_pkrtz(a.z, a.w);
  return u.v;
}
__device__ __forceinline__ float dot4(f32x4 a, f32x4 b) {
  return a.x * b.x + a.y * b.y + a.z * b.z + a.w * b.w;
}

// K=32 zero-shuffle B<->C chaining via k-permutation (r10-proven):
//   A-frag k-position (kt, q, j) holds W column F = 32kt + 16*(j>=4) + 4q + (j&3),
//   so the B operand = concat(C_frag[nt=2kt], C_frag[nt=2kt+1]) -- lane-local.
// Aggregate-before-matmul in f16 C-frag space (1x FLOPs). One barrier total.
//
// amdgpu_waves_per_eu(2,2): r9/r10/r11 all had VGPR_Count pinned at 128 with
// 114-246 MB of scratch spill (WRITE_SIZE) because the allocator targets the
// LDS-implied occupancy (34-42KB -> 4 blk/CU -> 128-reg clamp), ignoring
// launch_bounds' min-waves arg. Pinning waves/EU to 2 gives the 256-reg
// budget this ~150-reg live set needs. Do not remove.
__global__ __launch_bounds__(256)
__attribute__((amdgpu_waves_per_eu(2, 2)))
void gcn_fused(
    const float* __restrict__ x,
    const float* __restrict__ W1, const float* __restrict__ B1,
    const float* __restrict__ W2, const float* __restrict__ B2,
    const float* __restrict__ W3, const float* __restrict__ B3,
    const float* __restrict__ W4, const float* __restrict__ B4,
    const float* __restrict__ fcw, const float* __restrict__ fcb,
    float* __restrict__ out)
{
  __shared__ __align__(16) _Float16 wlds[4][4][2][64][8];  // [l][nt][kt][lane][8], k-permuted, cb-scaled
  __shared__ float blds[4][64];

  const int tid  = threadIdx.x;
  const int lane = tid & 63;
  const int c    = lane & 15;   // A-row local / C col (batch)
  const int q    = lane >> 4;   // k-group / C row-group
  const int w    = tid >> 6;
  const int b    = blockIdx.x * 64 + w * 16 + c;  // this lane's batch row

  const float* Wg[4] = {W1, W2, W3, W4};
  const int NB0[6] = {1, 0, 1, 2, 3, 3};
  const int NB1[6] = {2, 2, 3, 4, 5, 4};

  // ---- stage cb_l*W_l into LDS in k-permuted fragment order ----
#pragma unroll
  for (int l = 0; l < 4; ++l) {
    const float s = (l < 2) ? (1.f / 3.f) : 0.25f;
#pragma unroll
    for (int rep = 0; rep < 4; ++rep) {
      const int idx = rep * 1024 + tid * 4;       // flat f32 idx in 64x64 W_l
      const int row = idx >> 6, col = idx & 63;   // out-feat row, in-feat col
      const int nt = row >> 4, ca = row & 15;
      const int kt = col >> 5, ss = (col >> 4) & 1, qq = (col >> 2) & 3;
      f32x4 v = *(const f32x4*)(Wg[l] + idx);
      v *= s;
      *(f16x4*)&wlds[l][nt][kt][qq * 16 + ca][ss * 4] = cvt4(v);
    }
  }
  {  // biases: wave w stages layer w's bias
    const float* bp = (w == 0) ? B1 : (w == 1) ? B2 : (w == 2) ? B3 : B4;
    blds[w][lane] = bp[lane];
  }

  // ---- x -> hC (C-frag-order f16 regs) + residual fc-dot q-partials ----
  f16x4 hC[6][4];   // [node][m]: lane (c,q) holds feats m*16+4q+{0..3} of batch b
  float pacc[6];
  {
    const float* xr = x + (size_t)b * 384 + q * 4;
#pragma unroll
    for (int n = 0; n < 6; ++n) {
      float p = 0.f;
#pragma unroll
      for (int m = 0; m < 4; ++m) {
        f32x4 v  = *(const f32x4*)(xr + n * 64 + m * 16);
        f32x4 fw = *(const f32x4*)(fcw + n * 64 + m * 16 + q * 4);
        p += dot4(v, fw);
        hC[n][m] = cvt4(v);
      }
      pacc[n] = p;
    }
  }
  __syncthreads();  // staging visible; only barrier in the kernel

  float sv[6];
#pragma unroll
  for (int l = 0; l < 4; ++l) {
    // aggregate in f16 C-frag space (identical layouts across nodes); hC dies here
    f16x8 ag[6][2];
#pragma unroll
    for (int n = 0; n < 6; ++n)
#pragma unroll
      for (int kt = 0; kt < 2; ++kt) {
        f16x4 lo = hC[n][2 * kt]     + hC[NB0[n]][2 * kt]     + hC[NB1[n]][2 * kt];
        f16x4 hi = hC[n][2 * kt + 1] + hC[NB0[n]][2 * kt + 1] + hC[NB1[n]][2 * kt + 1];
        if (l >= 2) { lo = lo + hC[n][2 * kt]; hi = hi + hC[n][2 * kt + 1]; }  // ca=2cb
        ag[n][kt] = __builtin_shufflevector(lo, hi, 0, 1, 2, 3, 4, 5, 6, 7);
      }
    if (l == 3) {
#pragma unroll
      for (int n = 0; n < 6; ++n) sv[n] = pacc[n];
    }
#pragma unroll
    for (int nt = 0; nt < 4; ++nt) {
      const f16x8 wf0  = *(const f16x8*)&wlds[l][nt][0][lane][0];
      const f16x8 wf1  = *(const f16x8*)&wlds[l][nt][1][lane][0];
      const f32x4 bias = *(const f32x4*)&blds[l][nt * 16 + q * 4];
#pragma unroll
      for (int n = 0; n < 6; ++n) {
        f32x4 acc = __builtin_amdgcn_mfma_f32_16x16x32_f16(wf0, ag[n][0], bias, 0, 0, 0);
        acc = __builtin_amdgcn_mfma_f32_16x16x32_f16(wf1, ag[n][1], acc, 0, 0, 0);
        if (l < 3) {
          f32x4 r;
#pragma unroll
          for (int e = 0; e < 4; ++e) r[e] = fmaxf(acc[e], 0.f);
          hC[n][nt] = cvt4(r);   // C-frag IS the next layer's B half-frag
        } else {
          f32x4 fw = *(const f32x4*)(fcw + n * 64 + nt * 16 + q * 4);
#pragma unroll
          for (int e = 0; e < 4; ++e) sv[n] += fmaxf(acc[e], 0.f) * fw[e];
        }
      }
    }
  }

  // ---- epilogue: reduce fc-dot over q-groups, sigmoid, store ----
#pragma unroll
  for (int n = 0; n < 6; ++n) {
    float t = sv[n];
    t += __shfl_xor(t, 16, 64);
    t += __shfl_xor(t, 32, 64);
    if (q == 0) {
      const float vz = t + fcb[n];
      out[(size_t)b * 6 + n] = 1.f / (1.f + __expf(-vz));
    }
  }
}

extern "C" void kernel_launch(void* const* d_in, const int* in_sizes, int n_in,
                              void* d_out, int out_size, void* d_ws, size_t ws_size,
                              hipStream_t stream) {
  const float* x   = (const float*)d_in[0];
  const float* W1  = (const float*)d_in[1];
  const float* B1  = (const float*)d_in[2];
  const float* W2  = (const float*)d_in[3];
  const float* B2  = (const float*)d_in[4];
  const float* W3  = (const float*)d_in[5];
  const float* B3  = (const float*)d_in[6];
  const float* W4  = (const float*)d_in[7];
  const float* B4  = (const float*)d_in[8];
  const float* fcw = (const float*)d_in[9];
  const float* fcb = (const float*)d_in[10];
  float* out = (float*)d_out;

  const int batch  = in_sizes[0] / 384;   // 131072
  const int blocks = batch / 64;          // 4 waves x 16 batch rows per block
  hipLaunchKernelGGL(gcn_fused, dim3(blocks), dim3(256), 0, stream,
                     x, W1, B1, W2, B2, W3, B3, W4, B4, fcw, fcb, out);
}

// Round 13
// 101.938 us; speedup vs baseline: 1.5501x; 1.2587x over previous
//
#include <hip/hip_runtime.h>

typedef __attribute__((ext_vector_type(8))) _Float16 f16x8;
typedef __attribute__((ext_vector_type(4))) _Float16 f16x4;
typedef __attribute__((ext_vector_type(2))) __fp16 fp16x2;
typedef __attribute__((ext_vector_type(4))) float f32x4;

union U8 { f16x8 v; fp16x2 p[4]; };
union U4 { f16x4 v; fp16x2 p[2]; };

__device__ __forceinline__ f16x8 cvt8(f32x4 a, f32x4 b) {
  U8 u;
  u.p[0] = __builtin_amdgcn_cvt_pkrtz(a.x, a.y);
  u.p[1] = __builtin_amdgcn_cvt_pkrtz(a.z, a.w);
  u.p[2] = __builtin_amdgcn_cvt_pkrtz(b.x, b.y);
  u.p[3] = __builtin_amdgcn_cvt_pkrtz(b.z, b.w);
  return u.v;
}
__device__ __forceinline__ f16x4 cvt4(f32x4 a) {
  U4 u;
  u.p[0] = __builtin_amdgcn_cvt_pkrtz(a.x, a.y);
  u.p[1] = __builtin_amdgcn_cvt_pkrtz(a.z, a.w);
  return u.v;
}
__device__ __forceinline__ float dot4(f32x4 a, f32x4 b) {
  return a.x * b.x + a.y * b.y + a.z * b.z + a.w * b.w;
}

#define BT 16  // batch rows per block

// r5 block skeleton (flipped MFMA: A = W frag, B = h frag; C row=out-feat,
// col=batch; XOR-swizzled xs) with three fixes:
//  - W A-frags for ALL 4 layers preloaded into 32 regs (kills per-layer
//    global-load stalls before the MFMAs)
//  - double-buffered xs -> one barrier per layer (r5 had 2 + WAR hazard)
//  - matmul-first + per-lane f32 aggregation (1x FLOPs; r5 scatter was 3x)
// Live set ~100 arch VGPRs: fits the 128 arch-reg clamp (accum_offset split)
// that made every wave-private variant (r9-r12) spill 114-246 MB of scratch.
__global__ __launch_bounds__(256, 4) void gcn_fused(
    const float* __restrict__ x,
    const float* __restrict__ W1, const float* __restrict__ B1,
    const float* __restrict__ W2, const float* __restrict__ B2,
    const float* __restrict__ W3, const float* __restrict__ B3,
    const float* __restrict__ W4, const float* __restrict__ B4,
    const float* __restrict__ fcw, const float* __restrict__ fcb,
    float* __restrict__ out)
{
  __shared__ __align__(16) _Float16 xs[2][6 * BT * 64];  // double-buffered h
  __shared__ float pacc_s[6][BT];                        // residual x . fcw dots
  __shared__ float ls[BT][6];                            // logits staging

  const int tid  = threadIdx.x;
  const int lane = tid & 63;
  const int w    = tid >> 6;    // wave id = out-feature tile [16w,16w+16)
  const int c    = lane & 15;   // A-row local / C col (batch)
  const int q    = lane >> 4;   // k-group / C row-group
  const int b0   = blockIdx.x * BT;

  const float* Wg[4] = {W1, W2, W3, W4};
  const float* Bg[4] = {B1, B2, B3, B4};
  const int NB0[6] = {1, 0, 1, 2, 3, 3};
  const int NB1[6] = {2, 2, 3, 4, 5, 4};
  const f32x4 z4 = {0.f, 0.f, 0.f, 0.f};

  // ---- preload W A-frags, all 4 layers (r5 layout, unscaled): 32 regs ----
  f16x8 wfr[4][2];
#pragma unroll
  for (int l = 0; l < 4; ++l)
#pragma unroll
    for (int kf = 0; kf < 2; ++kf) {
      const float* wp = Wg[l] + (w * 16 + c) * 64 + kf * 32 + q * 8;
      wfr[l][kf] = cvt8(*(const f32x4*)wp, *(const f32x4*)(wp + 4));
    }

  // ---- stage x -> xs[0] (f16, swizzled) + residual fc-dot partials ----
  {
    const float* xb = x + (size_t)b0 * 384;
#pragma unroll
    for (int r = 0; r < 3; ++r) {
      const int i = tid * 8 + r * 2048;     // flat elem in 16x6x64 tile
      const int b = i / 384;
      const int rem = i - b * 384;
      const int n = rem >> 6;
      const int f = rem & 63;
      f32x4 v0 = *(const f32x4*)(xb + i);
      f32x4 v1 = *(const f32x4*)(xb + i + 4);
      const float* fw = fcw + n * 64 + f;
      float p = dot4(v0, *(const f32x4*)fw) + dot4(v1, *(const f32x4*)(fw + 4));
      p += __shfl_xor(p, 1, 64);
      p += __shfl_xor(p, 2, 64);
      p += __shfl_xor(p, 4, 64);
      if ((tid & 7) == 0) pacc_s[n][b] = p;
      const int slot = (f >> 3) ^ (b & 7);
      *(f16x8*)&xs[0][(n * BT + b) * 64 + slot * 8] = cvt8(v0, v1);
    }
  }
  __syncthreads();

  const int s1  = (q ^ (c & 7)) * 8;        // read slot, k = q*8..
  const int s2  = ((q + 4) ^ (c & 7)) * 8;  // read slot, k = 32+q*8..
  const int wsl = ((w * 2 + (q >> 1)) ^ (c & 7)) * 8 + (q & 1) * 4;  // write slot

  int cur = 0;
#pragma unroll
  for (int l = 0; l < 4; ++l) {
    const f32x4 bval = *(const f32x4*)(Bg[l] + w * 16 + q * 4);  // bias rows 4q+e
    // matmul per input node: acc[m] = W_l . h[m]  (bias NOT folded here)
    f32x4 acc[6];
#pragma unroll
    for (int m = 0; m < 6; ++m) {
      const _Float16* rp = &xs[cur][(m * BT + c) * 64];
      f16x8 a0 = *(const f16x8*)&rp[s1];
      f16x8 a1 = *(const f16x8*)&rp[s2];
      f32x4 d = __builtin_amdgcn_mfma_f32_16x16x32_f16(wfr[l][0], a0, z4, 0, 0, 0);
      acc[m]  = __builtin_amdgcn_mfma_f32_16x16x32_f16(wfr[l][1], a1, d, 0, 0, 0);
    }
    cur ^= 1;
    // per-lane aggregation (all nodes share C-frag layout) + bias + relu
#pragma unroll
    for (int n = 0; n < 6; ++n) {
      f32x4 t;
      if (l < 2) {
#pragma unroll
        for (int e = 0; e < 4; ++e)
          t[e] = (acc[n][e] + acc[NB0[n]][e] + acc[NB1[n]][e]) * (1.f / 3.f) + bval[e];
      } else {
#pragma unroll
        for (int e = 0; e < 4; ++e)
          t[e] = 0.5f * acc[n][e] + 0.25f * (acc[NB0[n]][e] + acc[NB1[n]][e]) + bval[e];
      }
#pragma unroll
      for (int e = 0; e < 4; ++e) t[e] = fmaxf(t[e], 0.f);
      // write feats w*16+4q+{0..3} of batch c into the other buffer
      *(f16x4*)&xs[cur][(n * BT + c) * 64 + wsl] = cvt4(t);
    }
    __syncthreads();
  }

  // ---- epilogue: broadcast-fcw A-frag; C rows all = dot(h4[b,n,:], fcw[n,:]) ----
  for (int n = w; n < 6; n += 4) {   // nodes split across waves
    const _Float16* rp = &xs[0][(n * BT + c) * 64];   // h4 lives in buffer 0
    f16x8 hb0 = *(const f16x8*)&rp[s1];
    f16x8 hb1 = *(const f16x8*)&rp[s2];
    const float* fw = fcw + n * 64 + q * 8;
    f16x8 fa0 = cvt8(*(const f32x4*)fw,        *(const f32x4*)(fw + 4));
    f16x8 fa1 = cvt8(*(const f32x4*)(fw + 32), *(const f32x4*)(fw + 36));
    f32x4 sv = __builtin_amdgcn_mfma_f32_16x16x32_f16(fa0, hb0, z4, 0, 0, 0);
    sv = __builtin_amdgcn_mfma_f32_16x16x32_f16(fa1, hb1, sv, 0, 0, 0);
    if (q == 0) {
      const float v = sv[0] + pacc_s[n][c] + fcb[n];
      ls[c][n] = 1.f / (1.f + __expf(-v));
    }
  }
  __syncthreads();
  if (tid < 96) out[(size_t)b0 * 6 + tid] = ((const float*)ls)[tid];
}

extern "C" void kernel_launch(void* const* d_in, const int* in_sizes, int n_in,
                              void* d_out, int out_size, void* d_ws, size_t ws_size,
                              hipStream_t stream) {
  const float* x   = (const float*)d_in[0];
  const float* W1  = (const float*)d_in[1];
  const float* B1  = (const float*)d_in[2];
  const float* W2  = (const float*)d_in[3];
  const float* B2  = (const float*)d_in[4];
  const float* W3  = (const float*)d_in[5];
  const float* B3  = (const float*)d_in[6];
  const float* W4  = (const float*)d_in[7];
  const float* B4  = (const float*)d_in[8];
  const float* fcw = (const float*)d_in[9];
  const float* fcb = (const float*)d_in[10];
  float* out = (float*)d_out;

  const int batch  = in_sizes[0] / 384;   // 131072
  const int blocks = batch / BT;          // one 16-batch tile per block
  hipLaunchKernelGGL(gcn_fused, dim3(blocks), dim3(256), 0, stream,
                     x, W1, B1, W2, B2, W3, B3, W4, B4, fcw, fcb, out);
}